// Round 3
// baseline (1407.877 us; speedup 1.0000x reference)
//
#include <hip/hip_runtime.h>
#include <math.h>

#define TPB 256

constexpr int Dd = 256;
constexpr int Nn = 1024;
constexpr int Mm = 1025;      // Nn + 1 (with dustbin)
constexpr int LDKc = 1040;    // padded row stride for K / KT (16-float aligned)
constexpr int SINK_ITERS = 100;
constexpr int GRID_NB = 257;  // persistent kernel blocks (<=2 per CU -> co-resident)

// ---- workspace layout (float offsets) ----
constexpr size_t OF_MD0   = 0;
constexpr size_t OF_MD1   = OF_MD0  + (size_t)Dd*Nn;
constexpr size_t OF_MD0T  = OF_MD1  + (size_t)Dd*Nn;
constexpr size_t OF_MD1T  = OF_MD0T + (size_t)Dd*Nn;
constexpr size_t OF_HA    = OF_MD1T + (size_t)Dd*Nn;
constexpr size_t OF_HBT   = OF_HA   + (size_t)Nn*64;
constexpr size_t OF_ZFA   = OF_HBT  + (size_t)Nn*64;
constexpr size_t OF_ZFB   = OF_ZFA  + (size_t)Nn*Dd;
constexpr size_t OF_WZ1T  = OF_ZFB  + (size_t)Nn*Dd;
constexpr size_t OF_WZ2T  = OF_WZ1T + (size_t)Dd*Dd;
constexpr size_t OF_ZA    = OF_WZ2T + (size_t)64*Dd;
constexpr size_t OF_ZB    = OF_ZA   + Nn;
constexpr size_t OF_ROWM  = OF_ZB   + Nn;
constexpr size_t OF_ROWS  = OF_ROWM + Nn;
constexpr size_t OF_CMP   = OF_ROWS + Nn;        // 16 x 1024 column partial max
constexpr size_t OF_CSP   = OF_CMP  + (size_t)16*Nn;
constexpr size_t OF_COLM  = OF_CSP  + (size_t)16*Nn;
constexpr size_t OF_COLS  = OF_COLM + Nn;
constexpr size_t OF_AV    = OF_COLS + Nn;             // a vector (exp(u))
constexpr size_t OF_BV    = OF_AV   + LDKc;           // b vector (exp(v))
constexpr size_t OF_RINV  = OF_BV   + LDKc;           // 1/rowsum
constexpr size_t OF_IDX0  = OF_RINV + LDKc;           // int
constexpr size_t OF_MAX0  = OF_IDX0 + Nn;
constexpr size_t OF_IDX1  = OF_MAX0 + Nn;             // int
constexpr size_t OF_CTR   = OF_IDX1 + Nn;             // unsigned barrier counter (16 floats reserved)
constexpr size_t OF_ATTN  = OF_CTR  + 16;
constexpr size_t OF_PART  = OF_ATTN;                  // zfeat partials: 4 x 262144 == attn size (attn dead)
constexpr size_t OF_PROBA = OF_ATTN + (size_t)Nn*Nn;
constexpr size_t OF_PROBB = OF_PROBA+ (size_t)Nn*Nn;
// K/KT alias attn/partials/probA region (dead before K is built)
constexpr size_t OF_K     = OF_ATTN;
constexpr size_t OF_KT    = OF_K + (size_t)Mm*LDKc;

// ---------- agent-scope (coherent-point) access helpers ----------
__device__ __forceinline__ float aloadf(const float* p) {
  return __hip_atomic_load((float*)p, __ATOMIC_RELAXED, __HIP_MEMORY_SCOPE_AGENT);
}
__device__ __forceinline__ int aloadi(const int* p) {
  return __hip_atomic_load((int*)p, __ATOMIC_RELAXED, __HIP_MEMORY_SCOPE_AGENT);
}
__device__ __forceinline__ void astoref(float* p, float v) {
  __hip_atomic_store(p, v, __ATOMIC_RELAXED, __HIP_MEMORY_SCOPE_AGENT);
}
__device__ __forceinline__ void astorei(int* p, int v) {
  __hip_atomic_store(p, v, __ATOMIC_RELAXED, __HIP_MEMORY_SCOPE_AGENT);
}

// grid barrier: __syncthreads drains vmcnt(0) per wave (so all sc-stores are at the
// coherence point) before thread0 arrives; spin on monotonic counter; compiler fence
// prevents hoisting subsequent loads above the spin.
__device__ __forceinline__ void gbar(unsigned* ctr, unsigned target) {
  __syncthreads();
  if (threadIdx.x == 0) {
    __hip_atomic_fetch_add(ctr, 1u, __ATOMIC_RELAXED, __HIP_MEMORY_SCOPE_AGENT);
    while (__hip_atomic_load(ctr, __ATOMIC_RELAXED, __HIP_MEMORY_SCOPE_AGENT) < target) {}
  }
  asm volatile("" ::: "memory");
  __syncthreads();
}

// mdesc = Wp @ desc + bp ; also writes transpose. grid (4, 64)
__global__ __launch_bounds__(TPB) void k_mdesc(const float* __restrict__ Wp,
                                               const float* __restrict__ bp,
                                               const float* __restrict__ desc,
                                               float* __restrict__ md,
                                               float* __restrict__ mdT) {
  int j = blockIdx.x * TPB + threadIdx.x;
  int d0 = blockIdx.y * 4;
  float acc[4] = {0.f, 0.f, 0.f, 0.f};
  for (int k = 0; k < Dd; ++k) {
    float v = desc[(size_t)k * Nn + j];
#pragma unroll
    for (int r = 0; r < 4; ++r) acc[r] += Wp[(size_t)(d0 + r) * Dd + k] * v;
  }
#pragma unroll
  for (int r = 0; r < 4; ++r) {
    acc[r] += bp[d0 + r];
    md[(size_t)(d0 + r) * Nn + j] = acc[r];
  }
  *(float4*)&mdT[(size_t)j * Dd + d0] = make_float4(acc[0], acc[1], acc[2], acc[3]);
}

// hA[n,o] / hBt[o,n]. grid (4,64,2)
__global__ __launch_bounds__(TPB) void k_h(const float* __restrict__ W1,
                                           const float* __restrict__ md0,
                                           const float* __restrict__ md1,
                                           float* __restrict__ hA,
                                           float* __restrict__ hBt) {
  int j = blockIdx.x * TPB + threadIdx.x;
  int o = blockIdx.y;
  int which = blockIdx.z;
  const float* md = which ? md1 : md0;
  const float* w = W1 + (size_t)o * 512 + which * 256;
  float acc = 0.f;
  for (int d = 0; d < Dd; ++d) acc += md[(size_t)d * Nn + j] * w[d];
  if (which == 0) hA[(size_t)j * 64 + o] = acc;
  else            hBt[(size_t)o * Nn + j] = acc;
}

// attn[i,j] = b2 + sum_o W2[o]*relu(hA[i,o]+hBt[o,j]+b1[o]). grid (4,256)
__global__ __launch_bounds__(TPB) void k_attn(const float* __restrict__ hA,
                                              const float* __restrict__ hBt,
                                              const float* __restrict__ W2,
                                              const float* __restrict__ b1,
                                              const float* __restrict__ b2,
                                              float* __restrict__ attn) {
  int j = blockIdx.x * TPB + threadIdx.x;
  int i0 = blockIdx.y * 4;
  float bias = b2[0];
  float acc[4] = {bias, bias, bias, bias};
  for (int o = 0; o < 64; ++o) {
    float hb = hBt[(size_t)o * Nn + j] + b1[o];
    float w = W2[o];
#pragma unroll
    for (int r = 0; r < 4; ++r) {
      float t = hA[(size_t)(i0 + r) * 64 + o] + hb;
      acc[r] += w * fmaxf(t, 0.f);
    }
  }
#pragma unroll
  for (int r = 0; r < 4; ++r) attn[(size_t)(i0 + r) * Nn + j] = acc[r];
}

// per-row softmax stats. grid 1024
__global__ __launch_bounds__(TPB) void k_rowstats(const float* __restrict__ attn,
                                                  float* __restrict__ rowM,
                                                  float* __restrict__ rowS) {
  int i = blockIdx.x, t = threadIdx.x;
  const float* row = attn + (size_t)i * Nn;
  float m = -INFINITY;
  for (int q = 0; q < 4; ++q) m = fmaxf(m, row[t + q * TPB]);
  __shared__ float red[TPB];
  red[t] = m; __syncthreads();
  for (int s = TPB / 2; s > 0; s >>= 1) {
    if (t < s) red[t] = fmaxf(red[t], red[t + s]);
    __syncthreads();
  }
  m = red[0]; __syncthreads();
  float ssum = 0.f;
  for (int q = 0; q < 4; ++q) ssum += expf(row[t + q * TPB] - m);
  red[t] = ssum; __syncthreads();
  for (int s = TPB / 2; s > 0; s >>= 1) {
    if (t < s) red[t] += red[t + s];
    __syncthreads();
  }
  if (t == 0) { rowM[i] = m; rowS[i] = red[0]; }
}

// column softmax stats, chunked over i. grid (4,16) then combine grid 4
__global__ __launch_bounds__(TPB) void k_colpart(const float* __restrict__ attn,
                                                 float* __restrict__ cmp,
                                                 float* __restrict__ csp) {
  int j = blockIdx.x * TPB + threadIdx.x;
  int c = blockIdx.y, i0 = c * 64;
  float m = -INFINITY;
  for (int q = 0; q < 64; ++q) m = fmaxf(m, attn[(size_t)(i0 + q) * Nn + j]);
  float s = 0.f;
  for (int q = 0; q < 64; ++q) s += expf(attn[(size_t)(i0 + q) * Nn + j] - m);
  cmp[(size_t)c * Nn + j] = m;
  csp[(size_t)c * Nn + j] = s;
}

__global__ __launch_bounds__(TPB) void k_colcomb(const float* __restrict__ cmp,
                                                 const float* __restrict__ csp,
                                                 float* __restrict__ colM,
                                                 float* __restrict__ colS) {
  int j = blockIdx.x * TPB + threadIdx.x;
  float m = -INFINITY;
  for (int c = 0; c < 16; ++c) m = fmaxf(m, cmp[(size_t)c * Nn + j]);
  float s = 0.f;
  for (int c = 0; c < 16; ++c) s += csp[(size_t)c * Nn + j] * expf(cmp[(size_t)c * Nn + j] - m);
  colM[j] = m; colS[j] = s;
}

// probA/probB materialization. grid (4,1024)
__global__ __launch_bounds__(TPB) void k_prob(const float* __restrict__ attn,
                                              const float* __restrict__ rowM,
                                              const float* __restrict__ rowS,
                                              const float* __restrict__ colM,
                                              const float* __restrict__ colS,
                                              float* __restrict__ probA,
                                              float* __restrict__ probB) {
  int j = blockIdx.x * TPB + threadIdx.x;
  int i = blockIdx.y;
  float v = attn[(size_t)i * Nn + j];
  probA[(size_t)i * Nn + j] = expf(v - rowM[i]) / rowS[i];
  probB[(size_t)i * Nn + j] = expf(v - colM[j]) / colS[j];
}

// zfeat partials: grid (256, 2, 2): x->4-row group, y->j half, z->side
__global__ __launch_bounds__(TPB) void k_zfeat_part(const float* __restrict__ probA,
                                                    const float* __restrict__ probB,
                                                    const float* __restrict__ md0T,
                                                    const float* __restrict__ md1T,
                                                    float* __restrict__ part) {
  int d = threadIdx.x;
  int r0 = blockIdx.x * 4;
  int jc = blockIdx.y;
  int side = blockIdx.z;
  const float* mdT  = side ? md0T : md1T;
  const float* prob = side ? probB : probA;
  int j0 = jc * 512;
  float acc[4] = {0.f, 0.f, 0.f, 0.f};
  if (side == 0) {
    for (int j = j0; j < j0 + 512; ++j) {
      float mv = mdT[(size_t)j * Dd + d];
#pragma unroll
      for (int r = 0; r < 4; ++r) acc[r] += prob[(size_t)(r0 + r) * Nn + j] * mv;
    }
  } else {
    for (int i = j0; i < j0 + 512; ++i) {
      float mv = mdT[(size_t)i * Dd + d];
#pragma unroll
      for (int r = 0; r < 4; ++r) acc[r] += prob[(size_t)i * Nn + (r0 + r)] * mv;
    }
  }
  float* dst = part + ((size_t)(side * 2 + jc)) * ((size_t)Nn * Dd);
#pragma unroll
  for (int r = 0; r < 4; ++r) dst[(size_t)(r0 + r) * Dd + d] = acc[r];
}

// combine partials: zf = p0 + p1. grid 2048
__global__ __launch_bounds__(TPB) void k_zfeat_comb(const float* __restrict__ part,
                                                    float* __restrict__ zfA,
                                                    float* __restrict__ zfB) {
  int idx = blockIdx.x * TPB + threadIdx.x;
  const size_t n = (size_t)Nn * Dd;
  if (idx < (int)n) zfA[idx] = part[idx] + part[n + idx];
  else {
    size_t k = (size_t)idx - n;
    zfB[k] = part[2 * n + k] + part[3 * n + k];
  }
}

// transpose Wz1 (256x256) and Wz2 (64x256). grid 320
__global__ __launch_bounds__(TPB) void k_transposeW(const float* __restrict__ Wz1,
                                                    const float* __restrict__ Wz2,
                                                    float* __restrict__ Wz1T,
                                                    float* __restrict__ Wz2T) {
  int t = threadIdx.x, b = blockIdx.x;
  if (b < 256) Wz1T[(size_t)t * 256 + b] = Wz1[(size_t)b * 256 + t];
  else {
    int o = b - 256;
    Wz2T[(size_t)t * 64 + o] = Wz2[(size_t)o * 256 + t];
  }
}

// zmlp over rows of zfeatA / zfeatB. grid (1024,2)
__global__ __launch_bounds__(TPB) void k_zmlp(const float* __restrict__ zfA,
                                              const float* __restrict__ zfB,
                                              const float* __restrict__ Wz1T,
                                              const float* __restrict__ bz1,
                                              const float* __restrict__ Wz2T,
                                              const float* __restrict__ bz2,
                                              const float* __restrict__ Wz3,
                                              const float* __restrict__ bz3,
                                              float* __restrict__ zA,
                                              float* __restrict__ zB) {
  int i = blockIdx.x, t = threadIdx.x, which = blockIdx.y;
  const float* x = (which ? zfB : zfA) + (size_t)i * Dd;
  __shared__ float xs[Dd];
  __shared__ float h1[Dd];
  __shared__ float h2[64];
  xs[t] = x[t];
  __syncthreads();
  float acc = bz1[t];
  for (int k = 0; k < Dd; ++k) acc += Wz1T[(size_t)k * Dd + t] * xs[k];
  h1[t] = fmaxf(acc, 0.f);
  __syncthreads();
  if (t < 64) {
    float a2 = bz2[t];
    for (int k = 0; k < Dd; ++k) a2 += Wz2T[(size_t)k * 64 + t] * h1[k];
    h2[t] = fmaxf(a2, 0.f);
  }
  __syncthreads();
  if (t < 64) {
    float p = Wz3[t] * h2[t];
#pragma unroll
    for (int off = 32; off > 0; off >>= 1) p += __shfl_down(p, off);
    if (t == 0) (which ? zB : zA)[i] = p + bz3[0];
  }
}

// K[i,j] = exp(scores[i,j]) for i,j<1024, also KT. grid (4,256)
__global__ __launch_bounds__(TPB) void k_buildK(const float* __restrict__ md0T,
                                                const float* __restrict__ md1,
                                                float* __restrict__ K,
                                                float* __restrict__ KT) {
  int j = blockIdx.x * TPB + threadIdx.x;
  int i0 = blockIdx.y * 4;
  float acc[4] = {0.f, 0.f, 0.f, 0.f};
  for (int d = 0; d < Dd; ++d) {
    float mv = md1[(size_t)d * Nn + j];
#pragma unroll
    for (int r = 0; r < 4; ++r) acc[r] += md0T[(size_t)(i0 + r) * Dd + d] * mv;
  }
  float vr[4];
#pragma unroll
  for (int r = 0; r < 4; ++r) {
    vr[r] = expf(acc[r] * 0.0625f);
    K[(size_t)(i0 + r) * LDKc + j] = vr[r];
  }
  *(float4*)&KT[(size_t)j * LDKc + i0] = make_float4(vr[0], vr[1], vr[2], vr[3]);
}

// dustbin row/col of K and KT; also resets barrier counter. grid 5
__global__ __launch_bounds__(TPB) void k_edgeK(const float* __restrict__ zA,
                                               const float* __restrict__ zB,
                                               float* __restrict__ K,
                                               float* __restrict__ KT,
                                               unsigned* __restrict__ ctr) {
  int idx = blockIdx.x * TPB + threadIdx.x;
  if (idx == 0) *ctr = 0u;
  if (idx >= Mm) return;
  const float E1 = 2.7182818284590452f;  // exp(alpha=1)
  float ka = (idx < Nn) ? expf(zA[idx]) : E1;  // K[idx][1024]
  float kb = (idx < Nn) ? expf(zB[idx]) : E1;  // K[1024][idx]
  K[(size_t)idx * LDKc + Nn] = ka;
  KT[(size_t)Nn * LDKc + idx] = ka;
  K[(size_t)Nn * LDKc + idx] = kb;
  KT[(size_t)idx * LDKc + Nn] = kb;
}

// wave dot of one K-row (global, per-XCD-L2-cached) with x staged in LDS.
__device__ __forceinline__ float rowdot(const float* __restrict__ row,
                                        const float* __restrict__ xs, int l) {
  float acc = 0.f;
#pragma unroll
  for (int q = 0; q < 16; ++q) {
    int j = l + 64 * q;
    acc += row[j] * xs[j];
  }
  if (l == 0) acc += row[1024] * xs[1024];
#pragma unroll
  for (int off = 32; off > 0; off >>= 1) acc += __shfl_xor(acc, off);
  return acc;
}

// persistent kernel: whole Sinkhorn + S + argmaxes + match. grid GRID_NB x TPB
__global__ __launch_bounds__(TPB, 1) void k_sink_persist(
    const float* __restrict__ K, const float* __restrict__ KT,
    float* __restrict__ av, float* __restrict__ bv, float* __restrict__ rinv,
    int* __restrict__ idx0, float* __restrict__ max0, int* __restrict__ idx1,
    unsigned* __restrict__ ctr, float* __restrict__ out) {
  const int bid = blockIdx.x;
  const int t = threadIdx.x;
  const int w = t >> 6, l = t & 63;
  const bool active = (bid < 256) || (w == 0);
  const int row = (bid < 256) ? (bid * 4 + w) : 1024;  // row of K; also col of K (row of KT)
  const float mu = (row < 1024) ? (1.0f / 2048.0f) : 0.5f;
  const float* krow = K + (size_t)row * LDKc;
  const float* trow = KT + (size_t)row * LDKc;

  __shared__ float xs[Mm];     // staged x-vector
  __shared__ float rs[Mm];     // staged rinv (epilogue)
  __shared__ float ms0[Nn];    // match scratch (block 0)
  __shared__ int v0s[Nn];
  __shared__ int i0s[Nn];

  unsigned tgt = GRID_NB;

  // ---- b = 1 ----
  int g = bid * TPB + t;
  if (g < Mm) astoref(&bv[g], 1.0f);
  gbar(ctr, tgt); tgt += GRID_NB;

  // ---- 100 Sinkhorn iterations (linear domain: a = mu/(K b); b = nu/(KT a)) ----
  for (int it = 0; it < SINK_ITERS; ++it) {
    for (int q = t; q < Mm; q += TPB) xs[q] = aloadf(&bv[q]);
    __syncthreads();
    if (active) {
      float acc = rowdot(krow, xs, l);
      if (l == 0) astoref(&av[row], mu / acc);
    }
    gbar(ctr, tgt); tgt += GRID_NB;

    for (int q = t; q < Mm; q += TPB) xs[q] = aloadf(&av[q]);
    __syncthreads();
    if (active) {
      float acc = rowdot(trow, xs, l);
      if (l == 0) astoref(&bv[row], mu / acc);
    }
    gbar(ctr, tgt); tgt += GRID_NB;
  }

  // ---- final row sums -> rinv ----
  for (int q = t; q < Mm; q += TPB) xs[q] = aloadf(&bv[q]);
  __syncthreads();
  if (active) {
    float acc = rowdot(krow, xs, l);
    if (l == 0) astoref(&rinv[row], 1.0f / acc);
  }
  gbar(ctr, tgt); tgt += GRID_NB;

  // ---- S rows + row argmax + col argmax ----
  for (int q = t; q < Mm; q += TPB) {
    xs[q] = aloadf(&bv[q]);
    rs[q] = aloadf(&rinv[q]);
  }
  __syncthreads();
  if (active) {
    float* srow = out + 4096 + (size_t)row * Mm;
    float ri = rs[row];
    float bm = -1.0f; int bj = 0;
#pragma unroll
    for (int q = 0; q < 16; ++q) {
      int j = l + 64 * q;
      float s = (krow[j] * xs[j]) * ri;
      srow[j] = s;
      if (s > bm) { bm = s; bj = j; }
    }
    if (l == 0) srow[1024] = (krow[1024] * xs[1024]) * ri;
    if (row < 1024) {
#pragma unroll
      for (int off = 32; off > 0; off >>= 1) {
        float om = __shfl_xor(bm, off);
        int oj = __shfl_xor(bj, off);
        if (om > bm || (om == bm && oj < bj)) { bm = om; bj = oj; }
      }
      if (l == 0) { astorei(&idx0[row], bj); astoref(&max0[row], bm); }
      // column argmax (bit-identical expression to the S entries)
      float bjv = xs[row];
      float cm = -1.0f; int ci = 0;
#pragma unroll
      for (int q = 0; q < 16; ++q) {
        int i = l + 64 * q;
        float v = (trow[i] * bjv) * rs[i];
        if (v > cm) { cm = v; ci = i; }
      }
#pragma unroll
      for (int off = 32; off > 0; off >>= 1) {
        float om = __shfl_xor(cm, off);
        int oi = __shfl_xor(ci, off);
        if (om > cm || (om == cm && oi < ci)) { cm = om; ci = oi; }
      }
      if (l == 0) astorei(&idx1[row], ci);
    }
  }
  gbar(ctr, tgt); tgt += GRID_NB;

  // ---- mutual matching (block 0) ----
  if (bid == 0) {
    for (int e = 0; e < 4; ++e) {
      int i = t + e * TPB;
      int j0 = aloadi(&idx0[i]);
      bool mut0 = (aloadi(&idx1[j0]) == i);
      // reference: mscores0 = exp(max of S-probability row)  (Round-2 bug: expf was missing)
      float m0v = mut0 ? expf(aloadf(&max0[i])) : 0.0f;
      bool val0 = mut0 && (m0v > 0.2f);
      ms0[i] = m0v; v0s[i] = val0 ? 1 : 0; i0s[i] = j0;
      out[i] = val0 ? (float)j0 : -1.0f;   // indices0
      out[2048 + i] = m0v;                  // mscores0
    }
    __syncthreads();
    for (int e = 0; e < 4; ++e) {
      int j = t + e * TPB;
      int i1 = aloadi(&idx1[j]);
      bool mut1 = (i0s[i1] == j);
      float m1v = mut1 ? ms0[i1] : 0.0f;
      bool val1 = mut1 && (v0s[i1] != 0);
      out[1024 + j] = val1 ? (float)i1 : -1.0f;  // indices1
      out[3072 + j] = m1v;                        // mscores1
    }
  }
}

extern "C" void kernel_launch(void* const* d_in, const int* in_sizes, int n_in,
                              void* d_out, int out_size, void* d_ws, size_t ws_size,
                              hipStream_t stream) {
  (void)in_sizes; (void)n_in; (void)out_size; (void)ws_size;
  const float* desc0 = (const float*)d_in[0];
  const float* desc1 = (const float*)d_in[1];
  const float* Wp    = (const float*)d_in[2];
  const float* bp    = (const float*)d_in[3];
  const float* W1    = (const float*)d_in[4];
  const float* b1    = (const float*)d_in[5];
  const float* W2    = (const float*)d_in[6];
  const float* b2    = (const float*)d_in[7];
  const float* Wz1   = (const float*)d_in[8];
  const float* bz1   = (const float*)d_in[9];
  const float* Wz2   = (const float*)d_in[10];
  const float* bz2   = (const float*)d_in[11];
  const float* Wz3   = (const float*)d_in[12];
  const float* bz3   = (const float*)d_in[13];
  float* ws  = (float*)d_ws;
  float* out = (float*)d_out;
  dim3 blk(TPB);

  k_mdesc<<<dim3(4, 64), blk, 0, stream>>>(Wp, bp, desc0, ws + OF_MD0, ws + OF_MD0T);
  k_mdesc<<<dim3(4, 64), blk, 0, stream>>>(Wp, bp, desc1, ws + OF_MD1, ws + OF_MD1T);
  k_h<<<dim3(4, 64, 2), blk, 0, stream>>>(W1, ws + OF_MD0, ws + OF_MD1, ws + OF_HA, ws + OF_HBT);
  k_attn<<<dim3(4, 256), blk, 0, stream>>>(ws + OF_HA, ws + OF_HBT, W2, b1, b2, ws + OF_ATTN);
  k_rowstats<<<dim3(1024), blk, 0, stream>>>(ws + OF_ATTN, ws + OF_ROWM, ws + OF_ROWS);
  k_colpart<<<dim3(4, 16), blk, 0, stream>>>(ws + OF_ATTN, ws + OF_CMP, ws + OF_CSP);
  k_colcomb<<<dim3(4), blk, 0, stream>>>(ws + OF_CMP, ws + OF_CSP, ws + OF_COLM, ws + OF_COLS);
  k_prob<<<dim3(4, 1024), blk, 0, stream>>>(ws + OF_ATTN, ws + OF_ROWM, ws + OF_ROWS,
                                            ws + OF_COLM, ws + OF_COLS,
                                            ws + OF_PROBA, ws + OF_PROBB);
  // attn region is dead now; partials alias it
  k_zfeat_part<<<dim3(256, 2, 2), blk, 0, stream>>>(ws + OF_PROBA, ws + OF_PROBB,
                                                    ws + OF_MD0T, ws + OF_MD1T,
                                                    ws + OF_PART);
  k_zfeat_comb<<<dim3(2048), blk, 0, stream>>>(ws + OF_PART, ws + OF_ZFA, ws + OF_ZFB);
  k_transposeW<<<dim3(320), blk, 0, stream>>>(Wz1, Wz2, ws + OF_WZ1T, ws + OF_WZ2T);
  k_zmlp<<<dim3(1024, 2), blk, 0, stream>>>(ws + OF_ZFA, ws + OF_ZFB,
                                            ws + OF_WZ1T, bz1, ws + OF_WZ2T, bz2,
                                            Wz3, bz3, ws + OF_ZA, ws + OF_ZB);
  // ---- K build (clobbers partials/probA region; both dead) ----
  k_buildK<<<dim3(4, 256), blk, 0, stream>>>(ws + OF_MD0T, ws + OF_MD1,
                                             ws + OF_K, ws + OF_KT);
  k_edgeK<<<dim3(5), blk, 0, stream>>>(ws + OF_ZA, ws + OF_ZB, ws + OF_K, ws + OF_KT,
                                       (unsigned*)(ws + OF_CTR));
  // ---- persistent Sinkhorn + S + argmax + match ----
  k_sink_persist<<<dim3(GRID_NB), blk, 0, stream>>>(
      ws + OF_K, ws + OF_KT, ws + OF_AV, ws + OF_BV, ws + OF_RINV,
      (int*)(ws + OF_IDX0), ws + OF_MAX0, (int*)(ws + OF_IDX1),
      (unsigned*)(ws + OF_CTR), out);
}

// Round 4
// 678.311 us; speedup vs baseline: 2.0756x; 2.0756x over previous
//
#include <hip/hip_runtime.h>
#include <math.h>

#define TPB 256

constexpr int Dd = 256;
constexpr int Nn = 1024;
constexpr int Mm = 1025;      // Nn + 1 (with dustbin)
constexpr int LDKc = 1040;    // padded row stride for K / KT (16-float aligned)
constexpr int SINK_ITERS = 100;
constexpr int NB  = 64;       // persistent blocks (distributed-flag barrier, 1 flag/lane)
constexpr int PT  = 1024;     // threads per persistent block (16 waves; 1 wave = 1 row)
constexpr int RPB = 16;       // rows per block (block 0 also owns row 1024)

// ---- workspace layout (float offsets) ----
constexpr size_t OF_MD0   = 0;
constexpr size_t OF_MD1   = OF_MD0  + (size_t)Dd*Nn;
constexpr size_t OF_MD0T  = OF_MD1  + (size_t)Dd*Nn;
constexpr size_t OF_MD1T  = OF_MD0T + (size_t)Dd*Nn;
constexpr size_t OF_HA    = OF_MD1T + (size_t)Dd*Nn;
constexpr size_t OF_HBT   = OF_HA   + (size_t)Nn*64;
constexpr size_t OF_ZFA   = OF_HBT  + (size_t)Nn*64;
constexpr size_t OF_ZFB   = OF_ZFA  + (size_t)Nn*Dd;
constexpr size_t OF_WZ1T  = OF_ZFB  + (size_t)Nn*Dd;
constexpr size_t OF_WZ2T  = OF_WZ1T + (size_t)Dd*Dd;
constexpr size_t OF_ZA    = OF_WZ2T + (size_t)64*Dd;
constexpr size_t OF_ZB    = OF_ZA   + Nn;
constexpr size_t OF_ROWM  = OF_ZB   + Nn;
constexpr size_t OF_ROWS  = OF_ROWM + Nn;
constexpr size_t OF_CMP   = OF_ROWS + Nn;        // 16 x 1024 column partial max
constexpr size_t OF_CSP   = OF_CMP  + (size_t)16*Nn;
constexpr size_t OF_COLM  = OF_CSP  + (size_t)16*Nn;
constexpr size_t OF_COLS  = OF_COLM + Nn;
constexpr size_t OF_AV    = OF_COLS + Nn;             // a vector (exp(u))
constexpr size_t OF_BV    = OF_AV   + LDKc;           // b vector (exp(v))
constexpr size_t OF_RINV  = OF_BV   + LDKc;           // 1/rowsum
constexpr size_t OF_IDX0  = OF_RINV + LDKc;           // int
constexpr size_t OF_MAX0  = OF_IDX0 + Nn;
constexpr size_t OF_IDX1  = OF_MAX0 + Nn;             // int
constexpr size_t OF_FLAGS = OF_IDX1 + Nn;             // 64 flags x 32-dword stride (8 KB)
constexpr size_t OF_ATTN  = OF_FLAGS + (size_t)64*32;
constexpr size_t OF_PART  = OF_ATTN;                  // zfeat partials alias attn (dead)
constexpr size_t OF_PROBA = OF_ATTN + (size_t)Nn*Nn;
constexpr size_t OF_PROBB = OF_PROBA+ (size_t)Nn*Nn;
// K/KT alias attn/partials/probA region (dead before K is built)
constexpr size_t OF_K     = OF_ATTN;
constexpr size_t OF_KT    = OF_K + (size_t)Mm*LDKc;

// ---------- agent-scope (coherence-point) access helpers ----------
__device__ __forceinline__ float aloadf(const float* p) {
  return __hip_atomic_load((float*)p, __ATOMIC_RELAXED, __HIP_MEMORY_SCOPE_AGENT);
}
__device__ __forceinline__ int aloadi(const int* p) {
  return __hip_atomic_load((int*)p, __ATOMIC_RELAXED, __HIP_MEMORY_SCOPE_AGENT);
}
__device__ __forceinline__ void astoref(float* p, float v) {
  __hip_atomic_store(p, v, __ATOMIC_RELAXED, __HIP_MEMORY_SCOPE_AGENT);
}
__device__ __forceinline__ void astorei(int* p, int v) {
  __hip_atomic_store(p, v, __ATOMIC_RELAXED, __HIP_MEMORY_SCOPE_AGENT);
}

// Distributed-flag grid barrier (NB=64): each block stores generation k to its own
// 128B-spaced flag (no RMW, parallel); wave 0 polls one flag per lane until all >= k.
// __syncthreads() first drains vmcnt(0) per wave -> all data stores are at the
// coherence point before the flag store.
__device__ __forceinline__ void gbar(unsigned* flags, unsigned k, int bid) {
  __syncthreads();
  if (threadIdx.x < 64) {
    if (threadIdx.x == 0)
      __hip_atomic_store(&flags[(size_t)bid * 32], k, __ATOMIC_RELAXED, __HIP_MEMORY_SCOPE_AGENT);
    while (true) {
      unsigned v = __hip_atomic_load(&flags[(size_t)threadIdx.x * 32],
                                     __ATOMIC_RELAXED, __HIP_MEMORY_SCOPE_AGENT);
      if (__all((int)(v >= k))) break;
      __builtin_amdgcn_s_sleep(1);
    }
  }
  asm volatile("" ::: "memory");
  __syncthreads();
}

// mdesc = Wp @ desc + bp ; also writes transpose. grid (4, 64)
__global__ __launch_bounds__(TPB) void k_mdesc(const float* __restrict__ Wp,
                                               const float* __restrict__ bp,
                                               const float* __restrict__ desc,
                                               float* __restrict__ md,
                                               float* __restrict__ mdT) {
  int j = blockIdx.x * TPB + threadIdx.x;
  int d0 = blockIdx.y * 4;
  float acc[4] = {0.f, 0.f, 0.f, 0.f};
  for (int k = 0; k < Dd; ++k) {
    float v = desc[(size_t)k * Nn + j];
#pragma unroll
    for (int r = 0; r < 4; ++r) acc[r] += Wp[(size_t)(d0 + r) * Dd + k] * v;
  }
#pragma unroll
  for (int r = 0; r < 4; ++r) {
    acc[r] += bp[d0 + r];
    md[(size_t)(d0 + r) * Nn + j] = acc[r];
  }
  *(float4*)&mdT[(size_t)j * Dd + d0] = make_float4(acc[0], acc[1], acc[2], acc[3]);
}

// hA[n,o] / hBt[o,n]. grid (4,64,2)
__global__ __launch_bounds__(TPB) void k_h(const float* __restrict__ W1,
                                           const float* __restrict__ md0,
                                           const float* __restrict__ md1,
                                           float* __restrict__ hA,
                                           float* __restrict__ hBt) {
  int j = blockIdx.x * TPB + threadIdx.x;
  int o = blockIdx.y;
  int which = blockIdx.z;
  const float* md = which ? md1 : md0;
  const float* w = W1 + (size_t)o * 512 + which * 256;
  float acc = 0.f;
  for (int d = 0; d < Dd; ++d) acc += md[(size_t)d * Nn + j] * w[d];
  if (which == 0) hA[(size_t)j * 64 + o] = acc;
  else            hBt[(size_t)o * Nn + j] = acc;
}

// attn[i,j] = b2 + sum_o W2[o]*relu(hA[i,o]+hBt[o,j]+b1[o]). grid (4,256)
__global__ __launch_bounds__(TPB) void k_attn(const float* __restrict__ hA,
                                              const float* __restrict__ hBt,
                                              const float* __restrict__ W2,
                                              const float* __restrict__ b1,
                                              const float* __restrict__ b2,
                                              float* __restrict__ attn) {
  int j = blockIdx.x * TPB + threadIdx.x;
  int i0 = blockIdx.y * 4;
  float bias = b2[0];
  float acc[4] = {bias, bias, bias, bias};
  for (int o = 0; o < 64; ++o) {
    float hb = hBt[(size_t)o * Nn + j] + b1[o];
    float w = W2[o];
#pragma unroll
    for (int r = 0; r < 4; ++r) {
      float t = hA[(size_t)(i0 + r) * 64 + o] + hb;
      acc[r] += w * fmaxf(t, 0.f);
    }
  }
#pragma unroll
  for (int r = 0; r < 4; ++r) attn[(size_t)(i0 + r) * Nn + j] = acc[r];
}

// per-row softmax stats. grid 1024
__global__ __launch_bounds__(TPB) void k_rowstats(const float* __restrict__ attn,
                                                  float* __restrict__ rowM,
                                                  float* __restrict__ rowS) {
  int i = blockIdx.x, t = threadIdx.x;
  const float* row = attn + (size_t)i * Nn;
  float m = -INFINITY;
  for (int q = 0; q < 4; ++q) m = fmaxf(m, row[t + q * TPB]);
  __shared__ float red[TPB];
  red[t] = m; __syncthreads();
  for (int s = TPB / 2; s > 0; s >>= 1) {
    if (t < s) red[t] = fmaxf(red[t], red[t + s]);
    __syncthreads();
  }
  m = red[0]; __syncthreads();
  float ssum = 0.f;
  for (int q = 0; q < 4; ++q) ssum += expf(row[t + q * TPB] - m);
  red[t] = ssum; __syncthreads();
  for (int s = TPB / 2; s > 0; s >>= 1) {
    if (t < s) red[t] += red[t + s];
    __syncthreads();
  }
  if (t == 0) { rowM[i] = m; rowS[i] = red[0]; }
}

// column softmax stats, chunked over i. grid (4,16) then combine grid 4
__global__ __launch_bounds__(TPB) void k_colpart(const float* __restrict__ attn,
                                                 float* __restrict__ cmp,
                                                 float* __restrict__ csp) {
  int j = blockIdx.x * TPB + threadIdx.x;
  int c = blockIdx.y, i0 = c * 64;
  float m = -INFINITY;
  for (int q = 0; q < 64; ++q) m = fmaxf(m, attn[(size_t)(i0 + q) * Nn + j]);
  float s = 0.f;
  for (int q = 0; q < 64; ++q) s += expf(attn[(size_t)(i0 + q) * Nn + j] - m);
  cmp[(size_t)c * Nn + j] = m;
  csp[(size_t)c * Nn + j] = s;
}

__global__ __launch_bounds__(TPB) void k_colcomb(const float* __restrict__ cmp,
                                                 const float* __restrict__ csp,
                                                 float* __restrict__ colM,
                                                 float* __restrict__ colS) {
  int j = blockIdx.x * TPB + threadIdx.x;
  float m = -INFINITY;
  for (int c = 0; c < 16; ++c) m = fmaxf(m, cmp[(size_t)c * Nn + j]);
  float s = 0.f;
  for (int c = 0; c < 16; ++c) s += csp[(size_t)c * Nn + j] * expf(cmp[(size_t)c * Nn + j] - m);
  colM[j] = m; colS[j] = s;
}

// probA/probB materialization. grid (4,1024)
__global__ __launch_bounds__(TPB) void k_prob(const float* __restrict__ attn,
                                              const float* __restrict__ rowM,
                                              const float* __restrict__ rowS,
                                              const float* __restrict__ colM,
                                              const float* __restrict__ colS,
                                              float* __restrict__ probA,
                                              float* __restrict__ probB) {
  int j = blockIdx.x * TPB + threadIdx.x;
  int i = blockIdx.y;
  float v = attn[(size_t)i * Nn + j];
  probA[(size_t)i * Nn + j] = expf(v - rowM[i]) / rowS[i];
  probB[(size_t)i * Nn + j] = expf(v - colM[j]) / colS[j];
}

// zfeat partials: grid (256, 2, 2): x->4-row group, y->j half, z->side
__global__ __launch_bounds__(TPB) void k_zfeat_part(const float* __restrict__ probA,
                                                    const float* __restrict__ probB,
                                                    const float* __restrict__ md0T,
                                                    const float* __restrict__ md1T,
                                                    float* __restrict__ part) {
  int d = threadIdx.x;
  int r0 = blockIdx.x * 4;
  int jc = blockIdx.y;
  int side = blockIdx.z;
  const float* mdT  = side ? md0T : md1T;
  const float* prob = side ? probB : probA;
  int j0 = jc * 512;
  float acc[4] = {0.f, 0.f, 0.f, 0.f};
  if (side == 0) {
    for (int j = j0; j < j0 + 512; ++j) {
      float mv = mdT[(size_t)j * Dd + d];
#pragma unroll
      for (int r = 0; r < 4; ++r) acc[r] += prob[(size_t)(r0 + r) * Nn + j] * mv;
    }
  } else {
    for (int i = j0; i < j0 + 512; ++i) {
      float mv = mdT[(size_t)i * Dd + d];
#pragma unroll
      for (int r = 0; r < 4; ++r) acc[r] += prob[(size_t)i * Nn + (r0 + r)] * mv;
    }
  }
  float* dst = part + ((size_t)(side * 2 + jc)) * ((size_t)Nn * Dd);
#pragma unroll
  for (int r = 0; r < 4; ++r) dst[(size_t)(r0 + r) * Dd + d] = acc[r];
}

// combine partials: zf = p0 + p1. grid 2048
__global__ __launch_bounds__(TPB) void k_zfeat_comb(const float* __restrict__ part,
                                                    float* __restrict__ zfA,
                                                    float* __restrict__ zfB) {
  int idx = blockIdx.x * TPB + threadIdx.x;
  const size_t n = (size_t)Nn * Dd;
  if (idx < (int)n) zfA[idx] = part[idx] + part[n + idx];
  else {
    size_t k = (size_t)idx - n;
    zfB[k] = part[2 * n + k] + part[3 * n + k];
  }
}

// transpose Wz1 (256x256) and Wz2 (64x256). grid 320
__global__ __launch_bounds__(TPB) void k_transposeW(const float* __restrict__ Wz1,
                                                    const float* __restrict__ Wz2,
                                                    float* __restrict__ Wz1T,
                                                    float* __restrict__ Wz2T) {
  int t = threadIdx.x, b = blockIdx.x;
  if (b < 256) Wz1T[(size_t)t * 256 + b] = Wz1[(size_t)b * 256 + t];
  else {
    int o = b - 256;
    Wz2T[(size_t)t * 64 + o] = Wz2[(size_t)o * 256 + t];
  }
}

// zmlp over rows of zfeatA / zfeatB. grid (1024,2)
__global__ __launch_bounds__(TPB) void k_zmlp(const float* __restrict__ zfA,
                                              const float* __restrict__ zfB,
                                              const float* __restrict__ Wz1T,
                                              const float* __restrict__ bz1,
                                              const float* __restrict__ Wz2T,
                                              const float* __restrict__ bz2,
                                              const float* __restrict__ Wz3,
                                              const float* __restrict__ bz3,
                                              float* __restrict__ zA,
                                              float* __restrict__ zB) {
  int i = blockIdx.x, t = threadIdx.x, which = blockIdx.y;
  const float* x = (which ? zfB : zfA) + (size_t)i * Dd;
  __shared__ float xs[Dd];
  __shared__ float h1[Dd];
  __shared__ float h2[64];
  xs[t] = x[t];
  __syncthreads();
  float acc = bz1[t];
  for (int k = 0; k < Dd; ++k) acc += Wz1T[(size_t)k * Dd + t] * xs[k];
  h1[t] = fmaxf(acc, 0.f);
  __syncthreads();
  if (t < 64) {
    float a2 = bz2[t];
    for (int k = 0; k < Dd; ++k) a2 += Wz2T[(size_t)k * 64 + t] * h1[k];
    h2[t] = fmaxf(a2, 0.f);
  }
  __syncthreads();
  if (t < 64) {
    float p = Wz3[t] * h2[t];
#pragma unroll
    for (int off = 32; off > 0; off >>= 1) p += __shfl_down(p, off);
    if (t == 0) (which ? zB : zA)[i] = p + bz3[0];
  }
}

// K[i,j] = exp(scores[i,j]) for i,j<1024, also KT. grid (4,256)
__global__ __launch_bounds__(TPB) void k_buildK(const float* __restrict__ md0T,
                                                const float* __restrict__ md1,
                                                float* __restrict__ K,
                                                float* __restrict__ KT) {
  int j = blockIdx.x * TPB + threadIdx.x;
  int i0 = blockIdx.y * 4;
  float acc[4] = {0.f, 0.f, 0.f, 0.f};
  for (int d = 0; d < Dd; ++d) {
    float mv = md1[(size_t)d * Nn + j];
#pragma unroll
    for (int r = 0; r < 4; ++r) acc[r] += md0T[(size_t)(i0 + r) * Dd + d] * mv;
  }
  float vr[4];
#pragma unroll
  for (int r = 0; r < 4; ++r) {
    vr[r] = expf(acc[r] * 0.0625f);
    K[(size_t)(i0 + r) * LDKc + j] = vr[r];
  }
  *(float4*)&KT[(size_t)j * LDKc + i0] = make_float4(vr[0], vr[1], vr[2], vr[3]);
}

// dustbin row/col of K and KT; also zeroes barrier flags. grid 8
__global__ __launch_bounds__(TPB) void k_edgeK(const float* __restrict__ zA,
                                               const float* __restrict__ zB,
                                               float* __restrict__ K,
                                               float* __restrict__ KT,
                                               unsigned* __restrict__ flags) {
  int idx = blockIdx.x * TPB + threadIdx.x;
  if (idx < NB * 32) flags[idx] = 0u;
  if (idx >= Mm) return;
  const float E1 = 2.7182818284590452f;  // exp(alpha=1)
  float ka = (idx < Nn) ? expf(zA[idx]) : E1;  // K[idx][1024]
  float kb = (idx < Nn) ? expf(zB[idx]) : E1;  // K[1024][idx]
  K[(size_t)idx * LDKc + Nn] = ka;
  KT[(size_t)Nn * LDKc + idx] = ka;
  K[(size_t)Nn * LDKc + idx] = kb;
  KT[(size_t)idx * LDKc + Nn] = kb;
}

// persistent kernel: whole Sinkhorn + S + argmaxes + match. grid NB x PT.
// Wave w of block b owns row r=b*16+w of K (a-updates) and of KT (b-updates);
// block 0 wave 0 additionally owns the dustbin row 1024. K/KT rows live in LDS.
__global__ __launch_bounds__(PT) void k_sink_persist(
    const float* __restrict__ K, const float* __restrict__ KT,
    float* __restrict__ av, float* __restrict__ bv, float* __restrict__ rinv,
    int* __restrict__ idx0, float* __restrict__ max0, int* __restrict__ idx1,
    unsigned* __restrict__ flags, float* __restrict__ out) {
  const int bid = blockIdx.x;
  const int t = threadIdx.x;
  const int w = t >> 6, l = t & 63;
  const int row = bid * RPB + w;             // 0..1023
  const bool extra = (bid == 0 && w == 0);   // also handles row 1024

  __shared__ float k_lds[17 * LDKc];   // 16 own K rows (+ row 1024 in slot 16 on block 0)
  __shared__ float t_lds[17 * LDKc];   // 16 own KT rows (+ row 1024 slot 16 on block 0)
  __shared__ float xs[LDKc];           // staged shared vector
  __shared__ float rs[LDKc];           // staged rinv (epilogue)

  // ---- stage K/KT rows into LDS (once) ----
  {
    const float* ksrc = K  + (size_t)bid * RPB * LDKc;
    const float* tsrc = KT + (size_t)bid * RPB * LDKc;
    for (int q = t; q < RPB * LDKc; q += PT) { k_lds[q] = ksrc[q]; t_lds[q] = tsrc[q]; }
    if (bid == 0) {
      const float* k24 = K  + (size_t)Nn * LDKc;
      const float* t24 = KT + (size_t)Nn * LDKc;
      for (int q = t; q < LDKc; q += PT) {
        k_lds[16 * LDKc + q] = k24[q];
        t_lds[16 * LDKc + q] = t24[q];
      }
    }
  }
  unsigned gen = 1;

  // ---- 200 Sinkhorn half-steps (h even: a = mu/(K b), b==1 at h=0; h odd: b = nu/(KT a)) ----
  for (int h = 0; h < 2 * SINK_ITERS; ++h) {
    const float* vec = (h & 1) ? av : bv;
    float* dst       = (h & 1) ? bv : av;
    const float* mat = (h & 1) ? t_lds : k_lds;
    if (h > 0) {
      for (int q = t; q < Mm; q += PT) xs[q] = aloadf(&vec[q]);
    }
    __syncthreads();
    {
      const float* r0 = mat + (size_t)w * LDKc;
      float acc = 0.f;
      if (h == 0) {
#pragma unroll
        for (int q = 0; q < 16; ++q) acc += r0[l + 64 * q];
        if (l == 0) acc += r0[1024];
      } else {
#pragma unroll
        for (int q = 0; q < 16; ++q) acc += r0[l + 64 * q] * xs[l + 64 * q];
        if (l == 0) acc += r0[1024] * xs[1024];
      }
#pragma unroll
      for (int off = 32; off > 0; off >>= 1) acc += __shfl_xor(acc, off);
      if (l == 0) astoref(&dst[row], (1.0f / 2048.0f) / acc);
    }
    if (extra) {
      const float* r0 = mat + (size_t)16 * LDKc;
      float acc = 0.f;
      if (h == 0) {
#pragma unroll
        for (int q = 0; q < 16; ++q) acc += r0[l + 64 * q];
        if (l == 0) acc += r0[1024];
      } else {
#pragma unroll
        for (int q = 0; q < 16; ++q) acc += r0[l + 64 * q] * xs[l + 64 * q];
        if (l == 0) acc += r0[1024] * xs[1024];
      }
#pragma unroll
      for (int off = 32; off > 0; off >>= 1) acc += __shfl_xor(acc, off);
      if (l == 0) astoref(&dst[1024], 0.5f / acc);
    }
    gbar(flags, gen, bid); ++gen;
  }

  // ---- final row sums -> rinv (x = b) ----
  for (int q = t; q < Mm; q += PT) xs[q] = aloadf(&bv[q]);
  __syncthreads();
  {
    const float* r0 = k_lds + (size_t)w * LDKc;
    float acc = 0.f;
#pragma unroll
    for (int q = 0; q < 16; ++q) acc += r0[l + 64 * q] * xs[l + 64 * q];
    if (l == 0) acc += r0[1024] * xs[1024];
#pragma unroll
    for (int off = 32; off > 0; off >>= 1) acc += __shfl_xor(acc, off);
    if (l == 0) astoref(&rinv[row], 1.0f / acc);
  }
  if (extra) {
    const float* r0 = k_lds + (size_t)16 * LDKc;
    float acc = 0.f;
#pragma unroll
    for (int q = 0; q < 16; ++q) acc += r0[l + 64 * q] * xs[l + 64 * q];
    if (l == 0) acc += r0[1024] * xs[1024];
#pragma unroll
    for (int off = 32; off > 0; off >>= 1) acc += __shfl_xor(acc, off);
    if (l == 0) astoref(&rinv[1024], 1.0f / acc);
  }
  gbar(flags, gen, bid); ++gen;

  // ---- S rows + row argmax + col argmax (xs still holds b) ----
  for (int q = t; q < Mm; q += PT) rs[q] = aloadf(&rinv[q]);
  __syncthreads();
  {
    const float* r0 = k_lds + (size_t)w * LDKc;
    float* srow = out + 4096 + (size_t)row * Mm;
    float ri = rs[row];
    float bm = -1.0f; int bj = 0;
#pragma unroll
    for (int q = 0; q < 16; ++q) {
      int j = l + 64 * q;
      float s = (r0[j] * xs[j]) * ri;
      srow[j] = s;
      if (s > bm) { bm = s; bj = j; }
    }
    if (l == 0) srow[1024] = (r0[1024] * xs[1024]) * ri;
#pragma unroll
    for (int off = 32; off > 0; off >>= 1) {
      float om = __shfl_xor(bm, off);
      int oj = __shfl_xor(bj, off);
      if (om > bm || (om == bm && oj < bj)) { bm = om; bj = oj; }
    }
    if (l == 0) { astorei(&idx0[row], bj); astoref(&max0[row], bm); }
    // column argmax over i<1024 for column `row` (identical fp expression to S entries)
    const float* t0 = t_lds + (size_t)w * LDKc;
    float bjv = xs[row];
    float cm = -1.0f; int ci = 0;
#pragma unroll
    for (int q = 0; q < 16; ++q) {
      int i = l + 64 * q;
      float v = (t0[i] * bjv) * rs[i];
      if (v > cm) { cm = v; ci = i; }
    }
#pragma unroll
    for (int off = 32; off > 0; off >>= 1) {
      float om = __shfl_xor(cm, off);
      int oi = __shfl_xor(ci, off);
      if (om > cm || (om == cm && oi < ci)) { cm = om; ci = oi; }
    }
    if (l == 0) astorei(&idx1[row], ci);
  }
  if (extra) {  // S row 1024 (no argmax)
    const float* r0 = k_lds + (size_t)16 * LDKc;
    float* srow = out + 4096 + (size_t)Nn * Mm;
    float ri = rs[1024];
#pragma unroll
    for (int q = 0; q < 16; ++q) {
      int j = l + 64 * q;
      srow[j] = (r0[j] * xs[j]) * ri;
    }
    if (l == 0) srow[1024] = (r0[1024] * xs[1024]) * ri;
  }
  gbar(flags, gen, bid); ++gen;

  // ---- mutual matching (block 0; scratch aliases k_lds, no longer needed) ----
  if (bid == 0) {
    float* ms0 = k_lds;
    int*   v0s = (int*)(k_lds + 1024);
    int*   i0s = (int*)(k_lds + 2048);
    int j0 = aloadi(&idx0[t]);
    bool mut0 = (aloadi(&idx1[j0]) == t);
    float m0v = mut0 ? expf(aloadf(&max0[t])) : 0.0f;  // mscores0 = exp(max log-prob)
    bool val0 = mut0 && (m0v > 0.2f);
    ms0[t] = m0v; v0s[t] = val0 ? 1 : 0; i0s[t] = j0;
    out[t] = val0 ? (float)j0 : -1.0f;   // indices0
    out[2048 + t] = m0v;                  // mscores0
    __syncthreads();
    int i1 = aloadi(&idx1[t]);
    bool mut1 = (i0s[i1] == t);
    float m1v = mut1 ? ms0[i1] : 0.0f;
    bool val1 = mut1 && (v0s[i1] != 0);
    out[1024 + t] = val1 ? (float)i1 : -1.0f;  // indices1
    out[3072 + t] = m1v;                        // mscores1
  }
}

extern "C" void kernel_launch(void* const* d_in, const int* in_sizes, int n_in,
                              void* d_out, int out_size, void* d_ws, size_t ws_size,
                              hipStream_t stream) {
  (void)in_sizes; (void)n_in; (void)out_size; (void)ws_size;
  const float* desc0 = (const float*)d_in[0];
  const float* desc1 = (const float*)d_in[1];
  const float* Wp    = (const float*)d_in[2];
  const float* bp    = (const float*)d_in[3];
  const float* W1    = (const float*)d_in[4];
  const float* b1    = (const float*)d_in[5];
  const float* W2    = (const float*)d_in[6];
  const float* b2    = (const float*)d_in[7];
  const float* Wz1   = (const float*)d_in[8];
  const float* bz1   = (const float*)d_in[9];
  const float* Wz2   = (const float*)d_in[10];
  const float* bz2   = (const float*)d_in[11];
  const float* Wz3   = (const float*)d_in[12];
  const float* bz3   = (const float*)d_in[13];
  float* ws  = (float*)d_ws;
  float* out = (float*)d_out;
  dim3 blk(TPB);

  k_mdesc<<<dim3(4, 64), blk, 0, stream>>>(Wp, bp, desc0, ws + OF_MD0, ws + OF_MD0T);
  k_mdesc<<<dim3(4, 64), blk, 0, stream>>>(Wp, bp, desc1, ws + OF_MD1, ws + OF_MD1T);
  k_h<<<dim3(4, 64, 2), blk, 0, stream>>>(W1, ws + OF_MD0, ws + OF_MD1, ws + OF_HA, ws + OF_HBT);
  k_attn<<<dim3(4, 256), blk, 0, stream>>>(ws + OF_HA, ws + OF_HBT, W2, b1, b2, ws + OF_ATTN);
  k_rowstats<<<dim3(1024), blk, 0, stream>>>(ws + OF_ATTN, ws + OF_ROWM, ws + OF_ROWS);
  k_colpart<<<dim3(4, 16), blk, 0, stream>>>(ws + OF_ATTN, ws + OF_CMP, ws + OF_CSP);
  k_colcomb<<<dim3(4), blk, 0, stream>>>(ws + OF_CMP, ws + OF_CSP, ws + OF_COLM, ws + OF_COLS);
  k_prob<<<dim3(4, 1024), blk, 0, stream>>>(ws + OF_ATTN, ws + OF_ROWM, ws + OF_ROWS,
                                            ws + OF_COLM, ws + OF_COLS,
                                            ws + OF_PROBA, ws + OF_PROBB);
  // attn region is dead now; partials alias it
  k_zfeat_part<<<dim3(256, 2, 2), blk, 0, stream>>>(ws + OF_PROBA, ws + OF_PROBB,
                                                    ws + OF_MD0T, ws + OF_MD1T,
                                                    ws + OF_PART);
  k_zfeat_comb<<<dim3(2048), blk, 0, stream>>>(ws + OF_PART, ws + OF_ZFA, ws + OF_ZFB);
  k_transposeW<<<dim3(320), blk, 0, stream>>>(Wz1, Wz2, ws + OF_WZ1T, ws + OF_WZ2T);
  k_zmlp<<<dim3(1024, 2), blk, 0, stream>>>(ws + OF_ZFA, ws + OF_ZFB,
                                            ws + OF_WZ1T, bz1, ws + OF_WZ2T, bz2,
                                            Wz3, bz3, ws + OF_ZA, ws + OF_ZB);
  // ---- K build (clobbers partials/probA region; both dead) ----
  k_buildK<<<dim3(4, 256), blk, 0, stream>>>(ws + OF_MD0T, ws + OF_MD1,
                                             ws + OF_K, ws + OF_KT);
  k_edgeK<<<dim3(8), blk, 0, stream>>>(ws + OF_ZA, ws + OF_ZB, ws + OF_K, ws + OF_KT,
                                       (unsigned*)(ws + OF_FLAGS));
  // ---- persistent Sinkhorn + S + argmax + match ----
  k_sink_persist<<<dim3(NB), dim3(PT), 0, stream>>>(
      ws + OF_K, ws + OF_KT, ws + OF_AV, ws + OF_BV, ws + OF_RINV,
      (int*)(ws + OF_IDX0), ws + OF_MAX0, (int*)(ws + OF_IDX1),
      (unsigned*)(ws + OF_FLAGS), out);
}